// Round 21
// baseline (123.677 us; speedup 1.0000x reference)
//
#include <hip/hip_runtime.h>

typedef float v4f __attribute__((ext_vector_type(4)));
typedef short v8s __attribute__((ext_vector_type(8)));

#define BM 64

__device__ __forceinline__ unsigned short f2bf(float f) {
    union { float f; unsigned u; } v; v.f = f;
    unsigned u = v.u;
    u += 0x7FFFu + ((u >> 16) & 1u);   // round-to-nearest-even
    return (unsigned short)(u >> 16);
}

__device__ __forceinline__ unsigned cvt_pk_bf16(float lo, float hi) {
    unsigned r;
    asm("v_cvt_pk_bf16_f32 %0, %1, %2" : "=v"(r) : "v"(lo), "v"(hi));
    return r;
}

#define LDS_BARRIER() do {                                        \
    asm volatile("s_waitcnt lgkmcnt(0)" ::: "memory");            \
    __builtin_amdgcn_s_barrier();                                 \
    __builtin_amdgcn_sched_barrier(0);                            \
} while (0)

#define SB() __builtin_amdgcn_sched_barrier(0)

__device__ __forceinline__ float fast_exp2(float x) {
#if __has_builtin(__builtin_amdgcn_exp2f)
    return __builtin_amdgcn_exp2f(x);
#else
    return exp2f(x);
#endif
}
__device__ __forceinline__ float fast_rcp(float x) {
#if __has_builtin(__builtin_amdgcn_rcpf)
    return __builtin_amdgcn_rcpf(x);
#else
    return 1.0f / x;
#endif
}
__device__ __forceinline__ float fast_tanh(float y) {
    float t = fast_exp2(y * 2.885390081777927f);
    return (t - 1.0f) * fast_rcp(t + 1.0f);
}
__device__ __forceinline__ float fast_sigmoid(float z) {
    float t = fast_exp2(-1.4426950408889634f * z);
    return fast_rcp(1.0f + t);
}

// ---------------------------------------------------------------------------
// Pack 5 weight matrices (fp32 row-major [N][K]) into bf16 MFMA-B-fragment
// order (canonical 16x32 tile: lane = ((k>>3)&3)*16 + (n&15), j = k&7).
// ws layout: Wb(98304) | W1(65536) | W2 | Wa | Wt   (bf16 elems)
// ---------------------------------------------------------------------------
__global__ void prep_pack(const float* __restrict__ Wb, const float* __restrict__ W1,
                          const float* __restrict__ W2, const float* __restrict__ Wa,
                          const float* __restrict__ Wt, unsigned short* __restrict__ ws)
{
    int e = blockIdx.x * 256 + threadIdx.x;
    if (e >= 360448) return;
    const float* src; int K; int base;
    if (e < 98304)       { src = Wb; K = 384; base = 0; }
    else if (e < 163840) { src = W1; K = 256; base = 98304; }
    else if (e < 229376) { src = W2; K = 256; base = 163840; }
    else if (e < 294912) { src = Wa; K = 256; base = 229376; }
    else                 { src = Wt; K = 256; base = 294912; }
    int le   = e - base;
    int j    = le & 7;
    int lane = (le >> 3) & 63;
    int tile = le >> 9;
    int kt   = K >> 5;
    int ks   = tile % kt;
    int nt   = tile / kt;
    int n = nt * 16 + (lane & 15);
    int k = ks * 32 + (lane >> 4) * 8 + j;
    ws[e] = f2bf(src[n * K + k]);
}

// ---------------------------------------------------------------------------
// KERNEL P1: X = lecun_tanh([in|hx] @ Wb^T + bb) -> Xg (bf16, packed A-frag
// layout, 32KB per 64-row block). R14 phase-1 structure verbatim (3-deep B
// rotation, ahead-2, 64-col LDS-staged chunks, per-step SB+setprio).
// (256,2): acc 64 AGPR + ~110 arch, proven no-spill.
// ---------------------------------------------------------------------------
__global__ __launch_bounds__(256, 2) void cfc_p1(
    const float* __restrict__ xin, const float* __restrict__ hx,
    const float* __restrict__ bb, const unsigned short* __restrict__ wpk,
    unsigned short* __restrict__ Xg)
{
    __shared__ unsigned short lds[16384];   // chunk [0,4096) overlay X [0,16384)
    const int tid  = threadIdx.x;
    const int lane = tid & 63;
    const int w    = tid >> 6;
    const int row0 = blockIdx.x * BM;

    v8s br0[4], br1[4], br2[4];

#define BLOADA(S, DST) do {                                                   \
    _Pragma("unroll")                                                         \
    for (int i = 0; i < 4; ++i) {                                             \
        size_t goff = (size_t)((w * 4 + i) * 12 + ((S) % 12)) * 512;          \
        DST[i] = *reinterpret_cast<const v8s*>(wpk + goff + (size_t)lane * 8);\
    }                                                                         \
} while (0)

#define ISSUE_INA(SRC, LD, BUF) do {                                          \
    _Pragma("unroll")                                                         \
    for (int it = 0; it < 4; ++it) {                                          \
        int i_ = tid + it * 256; int r_ = i_ >> 4; int c4_ = i_ & 15;         \
        BUF[it] = *(reinterpret_cast<const v4f*>((SRC) + (size_t)r_ * (LD)) + c4_); \
    }                                                                         \
} while (0)

#define WRITE_INA(BUF) do {                                                   \
    _Pragma("unroll")                                                         \
    for (int it = 0; it < 4; ++it) {                                          \
        int i_ = tid + it * 256; int r_ = i_ >> 4; int c4_ = i_ & 15;         \
        uint2 pk_;                                                            \
        pk_.x = cvt_pk_bf16(BUF[it][0], BUF[it][1]);                          \
        pk_.y = cvt_pk_bf16(BUF[it][2], BUF[it][3]);                          \
        int idx_ = (((r_ >> 4) * 2 + (c4_ >> 3)) * 64 + ((c4_ >> 1) & 3) * 16 \
                    + (r_ & 15)) * 8 + (c4_ & 1) * 4;                         \
        *reinterpret_cast<uint2*>(&lds[idx_]) = pk_;                          \
    }                                                                         \
} while (0)

#define P1STEPA(S, CUR, PRE) do {                                             \
    BLOADA((S) + 2, PRE);                                                     \
    v8s aa_[4];                                                               \
    _Pragma("unroll")                                                         \
    for (int mt = 0; mt < 4; ++mt)                                            \
        aa_[mt] = *reinterpret_cast<const v8s*>(                              \
                      &lds[((mt * 2 + ((S) & 1)) * 64 + lane) * 8]);          \
    __builtin_amdgcn_s_setprio(1);                                            \
    _Pragma("unroll")                                                         \
    for (int nt = 0; nt < 4; ++nt)                                            \
        _Pragma("unroll")                                                     \
        for (int mt = 0; mt < 4; ++mt)                                        \
            acc[nt][mt] = __builtin_amdgcn_mfma_f32_16x16x32_bf16(            \
                              aa_[mt], CUR[nt], acc[nt][mt], 0, 0, 0);        \
    __builtin_amdgcn_s_setprio(0);                                            \
    SB();                                                                     \
} while (0)

    v4f acc[4][4];
    #pragma unroll
    for (int nt = 0; nt < 4; ++nt) {
        float bv = bb[w * 64 + nt * 16 + (lane & 15)];
        v4f bvv = {bv, bv, bv, bv};
        #pragma unroll
        for (int mt = 0; mt < 4; ++mt) acc[nt][mt] = bvv;
    }

    v4f sA[4];
    ISSUE_INA(xin + (size_t)row0 * 128, 128, sA);
    BLOADA(0, br0); BLOADA(1, br1);
    WRITE_INA(sA);
    ISSUE_INA(xin + (size_t)row0 * 128 + 64, 128, sA);
    LDS_BARRIER();
    P1STEPA(0, br0, br2); P1STEPA(1, br1, br0);
    LDS_BARRIER();
    WRITE_INA(sA);
    ISSUE_INA(hx + (size_t)row0 * 256, 256, sA);
    LDS_BARRIER();
    P1STEPA(2, br2, br1); P1STEPA(3, br0, br2);
    LDS_BARRIER();
    WRITE_INA(sA);
    ISSUE_INA(hx + (size_t)row0 * 256 + 64, 256, sA);
    LDS_BARRIER();
    P1STEPA(4, br1, br0); P1STEPA(5, br2, br1);
    LDS_BARRIER();
    WRITE_INA(sA);
    ISSUE_INA(hx + (size_t)row0 * 256 + 128, 256, sA);
    LDS_BARRIER();
    P1STEPA(6, br0, br2); P1STEPA(7, br1, br0);
    LDS_BARRIER();
    WRITE_INA(sA);
    ISSUE_INA(hx + (size_t)row0 * 256 + 192, 256, sA);
    LDS_BARRIER();
    P1STEPA(8, br2, br1); P1STEPA(9, br0, br2);
    LDS_BARRIER();
    WRITE_INA(sA);
    LDS_BARRIER();
    P1STEPA(10, br1, br0); P1STEPA(11, br2, br1);

    LDS_BARRIER();                  // all waves done reading last input chunk

    // activation + pack X into LDS (A-frag layout), then coalesced copy out
    #pragma unroll
    for (int nt = 0; nt < 4; ++nt)
        #pragma unroll
        for (int mt = 0; mt < 4; ++mt)
            #pragma unroll
            for (int r = 0; r < 4; ++r) {
                float xv = 1.7159f * fast_tanh(0.666f * acc[nt][mt][r]);
                int idx = ((mt*8 + w*2 + (nt >> 1)) * 64
                           + ((nt & 1)*2 + ((lane >> 3) & 1)) * 16 + (lane >> 4)*4 + r) * 8
                          + (lane & 7);
                lds[idx] = f2bf(xv);
            }
    LDS_BARRIER();

    unsigned short* xb = Xg + (size_t)blockIdx.x * 16384;
    #pragma unroll
    for (int it = 0; it < 8; ++it) {
        int i = tid + it * 256;
        *reinterpret_cast<v8s*>(xb + (size_t)i * 8) =
            *reinterpret_cast<const v8s*>(&lds[i * 8]);
    }
#undef BLOADA
#undef ISSUE_INA
#undef WRITE_INA
#undef P1STEPA
}

// ---------------------------------------------------------------------------
// KERNEL P2: 4 GEMMs over packed X (L3-resident) + fused epilogue.
// ZERO LDS, ZERO barriers: A-fragments load directly from Xg (16B/lane
// coalesced, same layout P1 wrote); B via 2-deep reg rotation (ahead-1).
// (256,3): 64 AGPR + ~90 arch <= 106 avail -> 12 independent waves/CU.
// Flat 32 steps: S = g*8+ks; even S uses br0, odd br1.
// ---------------------------------------------------------------------------
__global__ __launch_bounds__(256, 3) void cfc_p2(
    const float* __restrict__ ts,
    const float* __restrict__ b1, const float* __restrict__ b2,
    const float* __restrict__ ba, const float* __restrict__ bt,
    const unsigned short* __restrict__ wpk,
    const unsigned short* __restrict__ Xg, float* __restrict__ out)
{
    const int tid  = threadIdx.x;
    const int lane = tid & 63;
    const int w    = tid >> 6;
    const int row0 = blockIdx.x * BM;
    const unsigned short* Xb = Xg + (size_t)blockIdx.x * 16384;

    v8s br0[4], br1[4];

#define BLOADB(S, DST) do {                                                   \
    _Pragma("unroll")                                                         \
    for (int i = 0; i < 4; ++i) {                                             \
        size_t goff = 98304u + (size_t)i * 65536                              \
                    + (size_t)(w * 32 + (S)) * 512;                           \
        DST[i] = *reinterpret_cast<const v8s*>(wpk + goff + (size_t)lane * 8);\
    }                                                                         \
} while (0)

#define P2BODYB(KS, CUR) do {                                                 \
    v8s aa_[4];                                                               \
    _Pragma("unroll")                                                         \
    for (int mt = 0; mt < 4; ++mt)                                            \
        aa_[mt] = *reinterpret_cast<const v8s*>(                              \
                      Xb + (size_t)(((mt * 8 + (KS)) * 64 + lane)) * 8);      \
    __builtin_amdgcn_s_setprio(1);                                            \
    _Pragma("unroll")                                                         \
    for (int mat = 0; mat < 4; ++mat)                                         \
        _Pragma("unroll")                                                     \
        for (int mt = 0; mt < 4; ++mt)                                        \
            a2[mat][mt] = __builtin_amdgcn_mfma_f32_16x16x32_bf16(            \
                              aa_[mt], CUR[mat], a2[mat][mt], 0, 0, 0);       \
    __builtin_amdgcn_s_setprio(0);                                            \
    SB();                                                                     \
} while (0)

#define P2SB(S, KS, CUR, PRE) do { BLOADB((S) + 1, PRE); P2BODYB(KS, CUR); } while (0)
#define P2SB_NS(S, KS, CUR)   do { P2BODYB(KS, CUR); } while (0)

#define GINITB(G) do {                                                        \
    const int n_ = w * 64 + (G) * 16 + (lane & 15);                           \
    float v1_ = b1[n_], v2_ = b2[n_], va_ = ba[n_], vt_ = bt[n_];             \
    v4f q1_ = {v1_,v1_,v1_,v1_}, q2_ = {v2_,v2_,v2_,v2_};                     \
    v4f qa_ = {va_,va_,va_,va_}, qt_ = {vt_,vt_,vt_,vt_};                     \
    _Pragma("unroll")                                                         \
    for (int mt = 0; mt < 4; ++mt) {                                          \
        a2[0][mt] = q1_; a2[1][mt] = q2_; a2[2][mt] = qa_; a2[3][mt] = qt_;   \
    }                                                                         \
} while (0)

#define EPIB(G) do {                                                          \
    const int n_ = w * 64 + (G) * 16 + (lane & 15);                           \
    _Pragma("unroll")                                                         \
    for (int mt = 0; mt < 4; ++mt) {                                          \
        int rowb_ = row0 + mt * 16 + ((lane >> 4) << 2);                      \
        v4f tsv_ = *reinterpret_cast<const v4f*>(&ts[rowb_]);                 \
        _Pragma("unroll")                                                     \
        for (int r = 0; r < 4; ++r) {                                         \
            float ff1_ = fast_tanh(a2[0][mt][r]);                             \
            float ff2_ = fast_tanh(a2[1][mt][r]);                             \
            float ti_  = fast_sigmoid(a2[2][mt][r] * tsv_[r] + a2[3][mt][r]); \
            out[(size_t)(rowb_ + r) * 256 + n_] = ff1_ + ti_ * (ff2_ - ff1_); \
        }                                                                     \
    }                                                                         \
} while (0)

    v4f a2[4][4];
    BLOADB(0, br0);

    GINITB(0);
    P2SB(0,0, br0, br1);  P2SB(1,1, br1, br0);
    P2SB(2,2, br0, br1);  P2SB(3,3, br1, br0);
    P2SB(4,4, br0, br1);  P2SB(5,5, br1, br0);
    P2SB(6,6, br0, br1);  P2SB(7,7, br1, br0);
    EPIB(0);
    GINITB(1);
    P2SB(8,0, br0, br1);  P2SB(9,1, br1, br0);
    P2SB(10,2, br0, br1); P2SB(11,3, br1, br0);
    P2SB(12,4, br0, br1); P2SB(13,5, br1, br0);
    P2SB(14,6, br0, br1); P2SB(15,7, br1, br0);
    EPIB(1);
    GINITB(2);
    P2SB(16,0, br0, br1); P2SB(17,1, br1, br0);
    P2SB(18,2, br0, br1); P2SB(19,3, br1, br0);
    P2SB(20,4, br0, br1); P2SB(21,5, br1, br0);
    P2SB(22,6, br0, br1); P2SB(23,7, br1, br0);
    EPIB(2);
    GINITB(3);
    P2SB(24,0, br0, br1); P2SB(25,1, br1, br0);
    P2SB(26,2, br0, br1); P2SB(27,3, br1, br0);
    P2SB(28,4, br0, br1); P2SB(29,5, br1, br0);
    P2SB(30,6, br0, br1); P2SB_NS(31,7, br1);
    EPIB(3);

#undef BLOADB
#undef P2BODYB
#undef P2SB
#undef P2SB_NS
#undef GINITB
#undef EPIB
}

// ---------------------------------------------------------------------------
// FALLBACK: R14 champion fused kernel (used if workspace too small for Xg).
// ---------------------------------------------------------------------------
__global__ __launch_bounds__(256, 2) void cfc_fused(
    const float* __restrict__ xin, const float* __restrict__ hx,
    const float* __restrict__ ts,
    const float* __restrict__ bb, const float* __restrict__ b1,
    const float* __restrict__ b2, const float* __restrict__ ba,
    const float* __restrict__ bt,
    const unsigned short* __restrict__ wpk,
    float* __restrict__ out)
{
    __shared__ unsigned short lds[16384];
    const int tid  = threadIdx.x;
    const int lane = tid & 63;
    const int w    = tid >> 6;
    const int row0 = blockIdx.x * BM;

    v8s br0[4], br1[4], br2[4];

#define BLOAD(S, DST) do {                                                    \
    _Pragma("unroll")                                                         \
    for (int i = 0; i < 4; ++i) {                                             \
        size_t goff;                                                          \
        if ((S) < 12) {                                                       \
            goff = (size_t)((w * 4 + i) * 12 + (S)) * 512;                    \
        } else {                                                              \
            int s2_ = (S) - 12, g_ = s2_ >> 3, ks_ = s2_ & 7;                 \
            goff = 98304u + (size_t)i * 65536                                 \
                 + (size_t)((w * 4 + g_) * 8 + ks_) * 512;                    \
        }                                                                     \
        DST[i] = *reinterpret_cast<const v8s*>(wpk + goff + (size_t)lane * 8);\
    }                                                                         \
} while (0)

#define ISSUE_IN(SRC, LD, BUF) do {                                           \
    _Pragma("unroll")                                                         \
    for (int it = 0; it < 4; ++it) {                                          \
        int i_ = tid + it * 256; int r_ = i_ >> 4; int c4_ = i_ & 15;         \
        BUF[it] = *(reinterpret_cast<const v4f*>((SRC) + (size_t)r_ * (LD)) + c4_); \
    }                                                                         \
} while (0)

#define WRITE_IN(BUF) do {                                                    \
    _Pragma("unroll")                                                         \
    for (int it = 0; it < 4; ++it) {                                          \
        int i_ = tid + it * 256; int r_ = i_ >> 4; int c4_ = i_ & 15;         \
        uint2 pk_;                                                            \
        pk_.x = cvt_pk_bf16(BUF[it][0], BUF[it][1]);                          \
        pk_.y = cvt_pk_bf16(BUF[it][2], BUF[it][3]);                          \
        int idx_ = (((r_ >> 4) * 2 + (c4_ >> 3)) * 64 + ((c4_ >> 1) & 3) * 16 \
                    + (r_ & 15)) * 8 + (c4_ & 1) * 4;                         \
        *reinterpret_cast<uint2*>(&lds[idx_]) = pk_;                          \
    }                                                                         \
} while (0)

#define P1STEP(S, CUR, PRE) do {                                              \
    BLOAD((S) + 2, PRE);                                                      \
    v8s aa_[4];                                                               \
    _Pragma("unroll")                                                         \
    for (int mt = 0; mt < 4; ++mt)                                            \
        aa_[mt] = *reinterpret_cast<const v8s*>(                              \
                      &lds[((mt * 2 + ((S) & 1)) * 64 + lane) * 8]);          \
    __builtin_amdgcn_s_setprio(1);                                            \
    _Pragma("unroll")                                                         \
    for (int nt = 0; nt < 4; ++nt)                                            \
        _Pragma("unroll")                                                     \
        for (int mt = 0; mt < 4; ++mt)                                        \
            acc[nt][mt] = __builtin_amdgcn_mfma_f32_16x16x32_bf16(            \
                              aa_[mt], CUR[nt], acc[nt][mt], 0, 0, 0);        \
    __builtin_amdgcn_s_setprio(0);                                            \
    SB();                                                                     \
} while (0)

#define P2STEP(S, KS, CUR, PRE) do {                                          \
    BLOAD((S) + 2, PRE);                                                      \
    v8s aa_[4];                                                               \
    _Pragma("unroll")                                                         \
    for (int mt = 0; mt < 4; ++mt)                                            \
        aa_[mt] = *reinterpret_cast<const v8s*>(                              \
                      &lds[((mt * 8 + (KS)) * 64 + lane) * 8]);               \
    __builtin_amdgcn_s_setprio(1);                                            \
    _Pragma("unroll")                                                         \
    for (int mat = 0; mat < 4; ++mat)                                         \
        _Pragma("unroll")                                                     \
        for (int mt = 0; mt < 4; ++mt)                                        \
            a2[mat][mt] = __builtin_amdgcn_mfma_f32_16x16x32_bf16(            \
                              aa_[mt], CUR[mat], a2[mat][mt], 0, 0, 0);       \
    __builtin_amdgcn_s_setprio(0);                                            \
    SB();                                                                     \
} while (0)

#define P2STEP_NS(S, KS, CUR) do {                                            \
    v8s aa_[4];                                                               \
    _Pragma("unroll")                                                         \
    for (int mt = 0; mt < 4; ++mt)                                            \
        aa_[mt] = *reinterpret_cast<const v8s*>(                              \
                      &lds[((mt * 8 + (KS)) * 64 + lane) * 8]);               \
    __builtin_amdgcn_s_setprio(1);                                            \
    _Pragma("unroll")                                                         \
    for (int mat = 0; mat < 4; ++mat)                                         \
        _Pragma("unroll")                                                     \
        for (int mt = 0; mt < 4; ++mt)                                        \
            a2[mat][mt] = __builtin_amdgcn_mfma_f32_16x16x32_bf16(            \
                              aa_[mt], CUR[mat], a2[mat][mt], 0, 0, 0);       \
    __builtin_amdgcn_s_setprio(0);                                            \
    SB();                                                                     \
} while (0)

#define GINIT(G) do {                                                         \
    const int n_ = w * 64 + (G) * 16 + (lane & 15);                           \
    float v1_ = b1[n_], v2_ = b2[n_], va_ = ba[n_], vt_ = bt[n_];             \
    v4f q1_ = {v1_,v1_,v1_,v1_}, q2_ = {v2_,v2_,v2_,v2_};                     \
    v4f qa_ = {va_,va_,va_,va_}, qt_ = {vt_,vt_,vt_,vt_};                     \
    _Pragma("unroll")                                                         \
    for (int mt = 0; mt < 4; ++mt) {                                          \
        a2[0][mt] = q1_; a2[1][mt] = q2_; a2[2][mt] = qa_; a2[3][mt] = qt_;   \
    }                                                                         \
} while (0)

#define EPI(G) do {                                                           \
    const int n_ = w * 64 + (G) * 16 + (lane & 15);                           \
    _Pragma("unroll")                                                         \
    for (int mt = 0; mt < 4; ++mt) {                                          \
        int rowb_ = row0 + mt * 16 + ((lane >> 4) << 2);                      \
        v4f tsv_ = *reinterpret_cast<const v4f*>(&ts[rowb_]);                 \
        _Pragma("unroll")                                                     \
        for (int r = 0; r < 4; ++r) {                                         \
            float ff1_ = fast_tanh(a2[0][mt][r]);                             \
            float ff2_ = fast_tanh(a2[1][mt][r]);                             \
            float ti_  = fast_sigmoid(a2[2][mt][r] * tsv_[r] + a2[3][mt][r]); \
            out[(size_t)(rowb_ + r) * 256 + n_] = ff1_ + ti_ * (ff2_ - ff1_); \
        }                                                                     \
    }                                                                         \
} while (0)

    v4f acc[4][4];
    #pragma unroll
    for (int nt = 0; nt < 4; ++nt) {
        float bv = bb[w * 64 + nt * 16 + (lane & 15)];
        v4f bvv = {bv, bv, bv, bv};
        #pragma unroll
        for (int mt = 0; mt < 4; ++mt) acc[nt][mt] = bvv;
    }

    v4f sA[4];
    ISSUE_IN(xin + (size_t)row0 * 128, 128, sA);
    BLOAD(0, br0); BLOAD(1, br1);
    WRITE_IN(sA);
    ISSUE_IN(xin + (size_t)row0 * 128 + 64, 128, sA);
    LDS_BARRIER();
    P1STEP(0, br0, br2); P1STEP(1, br1, br0);
    LDS_BARRIER();
    WRITE_IN(sA);
    ISSUE_IN(hx + (size_t)row0 * 256, 256, sA);
    LDS_BARRIER();
    P1STEP(2, br2, br1); P1STEP(3, br0, br2);
    LDS_BARRIER();
    WRITE_IN(sA);
    ISSUE_IN(hx + (size_t)row0 * 256 + 64, 256, sA);
    LDS_BARRIER();
    P1STEP(4, br1, br0); P1STEP(5, br2, br1);
    LDS_BARRIER();
    WRITE_IN(sA);
    ISSUE_IN(hx + (size_t)row0 * 256 + 128, 256, sA);
    LDS_BARRIER();
    P1STEP(6, br0, br2); P1STEP(7, br1, br0);
    LDS_BARRIER();
    WRITE_IN(sA);
    ISSUE_IN(hx + (size_t)row0 * 256 + 192, 256, sA);
    LDS_BARRIER();
    P1STEP(8, br2, br1); P1STEP(9, br0, br2);
    LDS_BARRIER();
    WRITE_IN(sA);
    LDS_BARRIER();
    P1STEP(10, br1, br0); P1STEP(11, br2, br1);

    LDS_BARRIER();

    #pragma unroll
    for (int nt = 0; nt < 4; ++nt)
        #pragma unroll
        for (int mt = 0; mt < 4; ++mt)
            #pragma unroll
            for (int r = 0; r < 4; ++r) {
                float xv = 1.7159f * fast_tanh(0.666f * acc[nt][mt][r]);
                int idx = ((mt*8 + w*2 + (nt >> 1)) * 64
                           + ((nt & 1)*2 + ((lane >> 3) & 1)) * 16 + (lane >> 4)*4 + r) * 8
                          + (lane & 7);
                lds[idx] = f2bf(xv);
            }
    LDS_BARRIER();

    v4f a2[4][4];
    GINIT(0);
    P2STEP(12,0, br0, br2); P2STEP(13,1, br1, br0);
    P2STEP(14,2, br2, br1); P2STEP(15,3, br0, br2);
    P2STEP(16,4, br1, br0); P2STEP(17,5, br2, br1);
    P2STEP(18,6, br0, br2); P2STEP(19,7, br1, br0);
    EPI(0);
    GINIT(1);
    P2STEP(20,0, br2, br1); P2STEP(21,1, br0, br2);
    P2STEP(22,2, br1, br0); P2STEP(23,3, br2, br1);
    P2STEP(24,4, br0, br2); P2STEP(25,5, br1, br0);
    P2STEP(26,6, br2, br1); P2STEP(27,7, br0, br2);
    EPI(1);
    GINIT(2);
    P2STEP(28,0, br1, br0); P2STEP(29,1, br2, br1);
    P2STEP(30,2, br0, br2); P2STEP(31,3, br1, br0);
    P2STEP(32,4, br2, br1); P2STEP(33,5, br0, br2);
    P2STEP(34,6, br1, br0); P2STEP(35,7, br2, br1);
    EPI(2);
    GINIT(3);
    P2STEP(36,0, br0, br2); P2STEP(37,1, br1, br0);
    P2STEP(38,2, br2, br1); P2STEP(39,3, br0, br2);
    P2STEP(40,4, br1, br0); P2STEP(41,5, br2, br1);
    P2STEP_NS(42,6, br0);   P2STEP_NS(43,7, br1);
    EPI(3);

#undef BLOAD
#undef ISSUE_IN
#undef WRITE_IN
#undef P1STEP
#undef P2STEP
#undef P2STEP_NS
#undef GINIT
#undef EPI
}

extern "C" void kernel_launch(void* const* d_in, const int* in_sizes, int n_in,
                              void* d_out, int out_size, void* d_ws, size_t ws_size,
                              hipStream_t stream)
{
    const float* xin = (const float*)d_in[0];
    const float* hx  = (const float*)d_in[1];
    const float* ts  = (const float*)d_in[2];
    const float* Wb  = (const float*)d_in[3];
    const float* bb  = (const float*)d_in[4];
    const float* W1  = (const float*)d_in[5];
    const float* b1  = (const float*)d_in[6];
    const float* W2  = (const float*)d_in[7];
    const float* b2  = (const float*)d_in[8];
    const float* Wa  = (const float*)d_in[9];
    const float* ba  = (const float*)d_in[10];
    const float* Wt  = (const float*)d_in[11];
    const float* bt  = (const float*)d_in[12];

    const size_t wpk_bytes = 360448ull * 2;                       // 720896
    const size_t xg_bytes  = 65536ull * 256 * 2;                  // 32 MB
    if (ws_size < wpk_bytes) return;

    unsigned short* wpk = (unsigned short*)d_ws;
    prep_pack<<<1408, 256, 0, stream>>>(Wb, W1, W2, Wa, Wt, wpk);

    if (ws_size >= wpk_bytes + xg_bytes) {
        unsigned short* Xg = wpk + 360448;
        cfc_p1<<<1024, 256, 0, stream>>>(xin, hx, bb, wpk, Xg);
        cfc_p2<<<1024, 256, 0, stream>>>(ts, b1, b2, ba, bt, wpk, Xg,
                                         (float*)d_out);
    } else {
        cfc_fused<<<1024, 256, 0, stream>>>(xin, hx, ts, bb, b1, b2, ba, bt,
                                            wpk, (float*)d_out);
    }
}

// Round 22
// 66.678 us; speedup vs baseline: 1.8548x; 1.8548x over previous
//
#include <hip/hip_runtime.h>

typedef float v4f __attribute__((ext_vector_type(4)));
typedef short v8s __attribute__((ext_vector_type(8)));

#define BM 64

__device__ __forceinline__ unsigned short f2bf(float f) {
    union { float f; unsigned u; } v; v.f = f;
    unsigned u = v.u;
    u += 0x7FFFu + ((u >> 16) & 1u);   // round-to-nearest-even
    return (unsigned short)(u >> 16);
}

// pack two f32 -> two bf16 (RNE) in one instruction
__device__ __forceinline__ unsigned cvt_pk_bf16(float lo, float hi) {
    unsigned r;
    asm("v_cvt_pk_bf16_f32 %0, %1, %2" : "=v"(r) : "v"(lo), "v"(hi));
    return r;
}

// shared-LDS sync WITHOUT draining vmcnt: only lgkm (ds ops) must complete;
// in-flight global loads into registers survive the barrier.
#define LDS_BARRIER() do {                                        \
    asm volatile("s_waitcnt lgkmcnt(0)" ::: "memory");            \
    __builtin_amdgcn_s_barrier();                                 \
    __builtin_amdgcn_sched_barrier(0);                            \
} while (0)

#define SB() __builtin_amdgcn_sched_barrier(0)

__device__ __forceinline__ float fast_exp2(float x) {
#if __has_builtin(__builtin_amdgcn_exp2f)
    return __builtin_amdgcn_exp2f(x);
#else
    return exp2f(x);
#endif
}
__device__ __forceinline__ float fast_rcp(float x) {
#if __has_builtin(__builtin_amdgcn_rcpf)
    return __builtin_amdgcn_rcpf(x);
#else
    return 1.0f / x;
#endif
}
__device__ __forceinline__ float fast_tanh(float y) {
    float t = fast_exp2(y * 2.885390081777927f);
    return (t - 1.0f) * fast_rcp(t + 1.0f);
}
__device__ __forceinline__ float fast_sigmoid(float z) {
    float t = fast_exp2(-1.4426950408889634f * z);
    return fast_rcp(1.0f + t);
}

// ---------------------------------------------------------------------------
// Pack 5 weight matrices (fp32 row-major [N][K]) into bf16 MFMA-B-fragment
// order (canonical 16x32 tile: lane = ((k>>3)&3)*16 + (n&15), j = k&7).
// ws layout: Wb(98304) | W1(65536) | W2 | Wa | Wt   (bf16 elems)
// ---------------------------------------------------------------------------
__global__ void prep_pack(const float* __restrict__ Wb, const float* __restrict__ W1,
                          const float* __restrict__ W2, const float* __restrict__ Wa,
                          const float* __restrict__ Wt, unsigned short* __restrict__ ws)
{
    int e = blockIdx.x * 256 + threadIdx.x;
    if (e >= 360448) return;
    const float* src; int K; int base;
    if (e < 98304)       { src = Wb; K = 384; base = 0; }
    else if (e < 163840) { src = W1; K = 256; base = 98304; }
    else if (e < 229376) { src = W2; K = 256; base = 163840; }
    else if (e < 294912) { src = Wa; K = 256; base = 229376; }
    else                 { src = Wt; K = 256; base = 294912; }
    int le   = e - base;
    int j    = le & 7;
    int lane = (le >> 3) & 63;
    int tile = le >> 9;
    int kt   = K >> 5;
    int ks   = tile % kt;
    int nt   = tile / kt;
    int n = nt * 16 + (lane & 15);
    int k = ks * 32 + (lane >> 4) * 8 + j;
    ws[e] = f2bf(src[n * K + k]);
}

// ---------------------------------------------------------------------------
// Fused CfC cell (R14 CHAMPION, restored verbatim).
// BM=64 rows/block, 4 waves each owning 64 output cols.
// Weights global->3-deep VGPR rotation br0/br1/br2 (issue-ahead-2, compiler-
// managed waitcnt). Register-dieted so arch-VGPR (~120) fits beside the
// 64-AGPR accumulator at __launch_bounds__(256,2): 64-col input chunks
// (single 16-reg staging buffer), in-step A-reads, ts loaded inside EPI.
// LDS 32KB (chunk 4KB overlaid on X 32KB). 2 blocks/CU; zero scratch spill.
// Flat 44 steps: 0..11 = phase 1 (6 chunks x 2 k-steps), 12..43 = phase 2.
//
// Session record (why this exact config): (256,3)/(170-reg cap), BM=128
// (128-AGPR acc), acc ping-pong, kernel split, full unroll, and manual
// vmcnt pipelines ALL spill (FETCH/WRITE +40..150MB signature) -- the
// 64-AGPR + ~120-arch working set fits exactly one configuration: this one.
// ---------------------------------------------------------------------------
__global__ __launch_bounds__(256, 2) void cfc_fused(
    const float* __restrict__ xin, const float* __restrict__ hx,
    const float* __restrict__ ts,
    const float* __restrict__ bb, const float* __restrict__ b1,
    const float* __restrict__ b2, const float* __restrict__ ba,
    const float* __restrict__ bt,
    const unsigned short* __restrict__ wpk,
    float* __restrict__ out)
{
    __shared__ unsigned short lds[16384];   // 32 KB: chunk [0,4096) / X [0,16384)
    const int tid  = threadIdx.x;
    const int lane = tid & 63;
    const int w    = tid >> 6;        // wave id = output-col group (64 cols)
    const int row0 = blockIdx.x * BM;

    v8s br0[4], br1[4], br2[4];       // 3-deep B rotation (48 VGPR)

// load step-S weight tile (4 x 16B/lane, coalesced) into DST regs
#define BLOAD(S, DST) do {                                                    \
    _Pragma("unroll")                                                         \
    for (int i = 0; i < 4; ++i) {                                             \
        size_t goff;                                                          \
        if ((S) < 12) {                                                       \
            goff = (size_t)((w * 4 + i) * 12 + (S)) * 512;                    \
        } else {                                                              \
            int s2_ = (S) - 12, g_ = s2_ >> 3, ks_ = s2_ & 7;                 \
            goff = 98304u + (size_t)i * 65536                                 \
                 + (size_t)((w * 4 + g_) * 8 + ks_) * 512;                    \
        }                                                                     \
        DST[i] = *reinterpret_cast<const v8s*>(wpk + goff + (size_t)lane * 8);\
    }                                                                         \
} while (0)

// 64-col input chunk: 64 rows x 16 v4f/row = 1024 v4f, 4 per thread
#define ISSUE_IN(SRC, LD, BUF) do {                                           \
    _Pragma("unroll")                                                         \
    for (int it = 0; it < 4; ++it) {                                          \
        int i_ = tid + it * 256; int r_ = i_ >> 4; int c4_ = i_ & 15;         \
        BUF[it] = *(reinterpret_cast<const v4f*>((SRC) + (size_t)r_ * (LD)) + c4_); \
    }                                                                         \
} while (0)

#define WRITE_IN(BUF) do {                                                    \
    _Pragma("unroll")                                                         \
    for (int it = 0; it < 4; ++it) {                                          \
        int i_ = tid + it * 256; int r_ = i_ >> 4; int c4_ = i_ & 15;         \
        uint2 pk_;                                                            \
        pk_.x = cvt_pk_bf16(BUF[it][0], BUF[it][1]);                          \
        pk_.y = cvt_pk_bf16(BUF[it][2], BUF[it][3]);                          \
        int idx_ = (((r_ >> 4) * 2 + (c4_ >> 3)) * 64 + ((c4_ >> 1) & 3) * 16 \
                    + (r_ & 15)) * 8 + (c4_ & 1) * 4;                         \
        *reinterpret_cast<uint2*>(&lds[idx_]) = pk_;                          \
    }                                                                         \
} while (0)

// phase-1 step: A in-step from chunk LDS (k-slice S&1), B from CUR regs
#define P1STEP(S, CUR, PRE) do {                                              \
    BLOAD((S) + 2, PRE);                                                      \
    v8s aa_[4];                                                               \
    _Pragma("unroll")                                                         \
    for (int mt = 0; mt < 4; ++mt)                                            \
        aa_[mt] = *reinterpret_cast<const v8s*>(                              \
                      &lds[((mt * 2 + ((S) & 1)) * 64 + lane) * 8]);          \
    __builtin_amdgcn_s_setprio(1);                                            \
    _Pragma("unroll")                                                         \
    for (int nt = 0; nt < 4; ++nt)                                            \
        _Pragma("unroll")                                                     \
        for (int mt = 0; mt < 4; ++mt)                                        \
            acc[nt][mt] = __builtin_amdgcn_mfma_f32_16x16x32_bf16(            \
                              aa_[mt], CUR[nt], acc[nt][mt], 0, 0, 0);        \
    __builtin_amdgcn_s_setprio(0);                                            \
    SB();                                                                     \
} while (0)

// phase-2 step: A in-step from X LDS, B from CUR regs, prefetch S+2 -> PRE
#define P2STEP(S, KS, CUR, PRE) do {                                          \
    BLOAD((S) + 2, PRE);                                                      \
    v8s aa_[4];                                                               \
    _Pragma("unroll")                                                         \
    for (int mt = 0; mt < 4; ++mt)                                            \
        aa_[mt] = *reinterpret_cast<const v8s*>(                              \
                      &lds[((mt * 8 + (KS)) * 64 + lane) * 8]);               \
    __builtin_amdgcn_s_setprio(1);                                            \
    _Pragma("unroll")                                                         \
    for (int mat = 0; mat < 4; ++mat)                                         \
        _Pragma("unroll")                                                     \
        for (int mt = 0; mt < 4; ++mt)                                        \
            a2[mat][mt] = __builtin_amdgcn_mfma_f32_16x16x32_bf16(            \
                              aa_[mt], CUR[mat], a2[mat][mt], 0, 0, 0);       \
    __builtin_amdgcn_s_setprio(0);                                            \
    SB();                                                                     \
} while (0)

// tail variant: no weight prefetch
#define P2STEP_NS(S, KS, CUR) do {                                            \
    v8s aa_[4];                                                               \
    _Pragma("unroll")                                                         \
    for (int mt = 0; mt < 4; ++mt)                                            \
        aa_[mt] = *reinterpret_cast<const v8s*>(                              \
                      &lds[((mt * 8 + (KS)) * 64 + lane) * 8]);               \
    __builtin_amdgcn_s_setprio(1);                                            \
    _Pragma("unroll")                                                         \
    for (int mat = 0; mat < 4; ++mat)                                         \
        _Pragma("unroll")                                                     \
        for (int mt = 0; mt < 4; ++mt)                                        \
            a2[mat][mt] = __builtin_amdgcn_mfma_f32_16x16x32_bf16(            \
                              aa_[mt], CUR[mat], a2[mat][mt], 0, 0, 0);       \
    __builtin_amdgcn_s_setprio(0);                                            \
    SB();                                                                     \
} while (0)

#define GINIT(G) do {                                                         \
    const int n_ = w * 64 + (G) * 16 + (lane & 15);                           \
    float v1_ = b1[n_], v2_ = b2[n_], va_ = ba[n_], vt_ = bt[n_];             \
    v4f q1_ = {v1_,v1_,v1_,v1_}, q2_ = {v2_,v2_,v2_,v2_};                     \
    v4f qa_ = {va_,va_,va_,va_}, qt_ = {vt_,vt_,vt_,vt_};                     \
    _Pragma("unroll")                                                         \
    for (int mt = 0; mt < 4; ++mt) {                                          \
        a2[0][mt] = q1_; a2[1][mt] = q2_; a2[2][mt] = qa_; a2[3][mt] = qt_;   \
    }                                                                         \
} while (0)

#define EPI(G) do {                                                           \
    const int n_ = w * 64 + (G) * 16 + (lane & 15);                           \
    _Pragma("unroll")                                                         \
    for (int mt = 0; mt < 4; ++mt) {                                          \
        int rowb_ = row0 + mt * 16 + ((lane >> 4) << 2);                      \
        v4f tsv_ = *reinterpret_cast<const v4f*>(&ts[rowb_]);                 \
        _Pragma("unroll")                                                     \
        for (int r = 0; r < 4; ++r) {                                         \
            float ff1_ = fast_tanh(a2[0][mt][r]);                             \
            float ff2_ = fast_tanh(a2[1][mt][r]);                             \
            float ti_  = fast_sigmoid(a2[2][mt][r] * tsv_[r] + a2[3][mt][r]); \
            out[(size_t)(rowb_ + r) * 256 + n_] = ff1_ + ti_ * (ff2_ - ff1_); \
        }                                                                     \
    }                                                                         \
} while (0)

    // ---------------- phase 1: backbone GEMM, acc[nt][mt] -------------------
    v4f acc[4][4];
    #pragma unroll
    for (int nt = 0; nt < 4; ++nt) {
        float bv = bb[w * 64 + nt * 16 + (lane & 15)];
        v4f bvv = {bv, bv, bv, bv};
        #pragma unroll
        for (int mt = 0; mt < 4; ++mt) acc[nt][mt] = bvv;
    }

    v4f sA[4];
    // chunk 0: in cols [0,64)
    ISSUE_IN(xin + (size_t)row0 * 128, 128, sA);
    BLOAD(0, br0); BLOAD(1, br1);       // weight pipeline: 2 tiles in flight
    WRITE_IN(sA);
    ISSUE_IN(xin + (size_t)row0 * 128 + 64, 128, sA);     // chunk 1 prefetch
    LDS_BARRIER();
    P1STEP(0, br0, br2); P1STEP(1, br1, br0);
    LDS_BARRIER();                      // chunk 0 consumed by all waves
    WRITE_IN(sA);
    ISSUE_IN(hx + (size_t)row0 * 256, 256, sA);           // chunk 2 prefetch
    LDS_BARRIER();
    P1STEP(2, br2, br1); P1STEP(3, br0, br2);
    LDS_BARRIER();
    WRITE_IN(sA);
    ISSUE_IN(hx + (size_t)row0 * 256 + 64, 256, sA);      // chunk 3 prefetch
    LDS_BARRIER();
    P1STEP(4, br1, br0); P1STEP(5, br2, br1);
    LDS_BARRIER();
    WRITE_IN(sA);
    ISSUE_IN(hx + (size_t)row0 * 256 + 128, 256, sA);     // chunk 4 prefetch
    LDS_BARRIER();
    P1STEP(6, br0, br2); P1STEP(7, br1, br0);
    LDS_BARRIER();
    WRITE_IN(sA);
    ISSUE_IN(hx + (size_t)row0 * 256 + 192, 256, sA);     // chunk 5 prefetch
    LDS_BARRIER();
    P1STEP(8, br2, br1); P1STEP(9, br0, br2);
    LDS_BARRIER();
    WRITE_IN(sA);
    LDS_BARRIER();
    P1STEP(10, br1, br0); P1STEP(11, br2, br1);

    LDS_BARRIER();                  // all waves done reading last input chunk

    // ------------- activation + write X to LDS in packed A-frag layout ------
    #pragma unroll
    for (int nt = 0; nt < 4; ++nt)
        #pragma unroll
        for (int mt = 0; mt < 4; ++mt)
            #pragma unroll
            for (int r = 0; r < 4; ++r) {
                float xv = 1.7159f * fast_tanh(0.666f * acc[nt][mt][r]);
                int idx = ((mt*8 + w*2 + (nt >> 1)) * 64
                           + ((nt & 1)*2 + ((lane >> 3) & 1)) * 16 + (lane >> 4)*4 + r) * 8
                          + (lane & 7);
                lds[idx] = f2bf(xv);
            }
    LDS_BARRIER();                  // X visible to all waves

    // ---------------- phase 2: 4 GEMMs over X + fused epilogue --------------
    v4f a2[4][4];
    GINIT(0);
    P2STEP(12,0, br0, br2); P2STEP(13,1, br1, br0);
    P2STEP(14,2, br2, br1); P2STEP(15,3, br0, br2);
    P2STEP(16,4, br1, br0); P2STEP(17,5, br2, br1);
    P2STEP(18,6, br0, br2); P2STEP(19,7, br1, br0);
    EPI(0);
    GINIT(1);
    P2STEP(20,0, br2, br1); P2STEP(21,1, br0, br2);
    P2STEP(22,2, br1, br0); P2STEP(23,3, br2, br1);
    P2STEP(24,4, br0, br2); P2STEP(25,5, br1, br0);
    P2STEP(26,6, br2, br1); P2STEP(27,7, br0, br2);
    EPI(1);
    GINIT(2);
    P2STEP(28,0, br1, br0); P2STEP(29,1, br2, br1);
    P2STEP(30,2, br0, br2); P2STEP(31,3, br1, br0);
    P2STEP(32,4, br2, br1); P2STEP(33,5, br0, br2);
    P2STEP(34,6, br1, br0); P2STEP(35,7, br2, br1);
    EPI(2);
    GINIT(3);
    P2STEP(36,0, br0, br2); P2STEP(37,1, br1, br0);
    P2STEP(38,2, br2, br1); P2STEP(39,3, br0, br2);
    P2STEP(40,4, br1, br0); P2STEP(41,5, br2, br1);
    P2STEP_NS(42,6, br0);   P2STEP_NS(43,7, br1);
    EPI(3);

#undef BLOAD
#undef ISSUE_IN
#undef WRITE_IN
#undef P1STEP
#undef P2STEP
#undef P2STEP_NS
#undef GINIT
#undef EPI
}

extern "C" void kernel_launch(void* const* d_in, const int* in_sizes, int n_in,
                              void* d_out, int out_size, void* d_ws, size_t ws_size,
                              hipStream_t stream)
{
    const float* xin = (const float*)d_in[0];
    const float* hx  = (const float*)d_in[1];
    const float* ts  = (const float*)d_in[2];
    const float* Wb  = (const float*)d_in[3];
    const float* bb  = (const float*)d_in[4];
    const float* W1  = (const float*)d_in[5];
    const float* b1  = (const float*)d_in[6];
    const float* W2  = (const float*)d_in[7];
    const float* b2  = (const float*)d_in[8];
    const float* Wa  = (const float*)d_in[9];
    const float* ba  = (const float*)d_in[10];
    const float* Wt  = (const float*)d_in[11];
    const float* bt  = (const float*)d_in[12];

    if (ws_size < 360448 * sizeof(unsigned short)) return;
    unsigned short* wpk = (unsigned short*)d_ws;

    prep_pack<<<1408, 256, 0, stream>>>(Wb, W1, W2, Wa, Wt, wpk);
    cfc_fused<<<1024, 256, 0, stream>>>(xin, hx, ts, bb, b1, b2, ba, bt, wpk,
                                        (float*)d_out);
}

// Round 24
// 66.247 us; speedup vs baseline: 1.8669x; 1.0065x over previous
//
#include <hip/hip_runtime.h>

typedef float v4f __attribute__((ext_vector_type(4)));
typedef short v8s __attribute__((ext_vector_type(8)));

#define BM 64

__device__ __forceinline__ unsigned short f2bf(float f) {
    union { float f; unsigned u; } v; v.f = f;
    unsigned u = v.u;
    u += 0x7FFFu + ((u >> 16) & 1u);   // round-to-nearest-even
    return (unsigned short)(u >> 16);
}

// pack two f32 -> two bf16 (RNE) in one instruction
__device__ __forceinline__ unsigned cvt_pk_bf16(float lo, float hi) {
    unsigned r;
    asm("v_cvt_pk_bf16_f32 %0, %1, %2" : "=v"(r) : "v"(lo), "v"(hi));
    return r;
}

// shared-LDS sync WITHOUT draining vmcnt: only lgkm (ds ops) must complete;
// in-flight global loads into registers survive the barrier.
#define LDS_BARRIER() do {                                        \
    asm volatile("s_waitcnt lgkmcnt(0)" ::: "memory");            \
    __builtin_amdgcn_s_barrier();                                 \
    __builtin_amdgcn_sched_barrier(0);                            \
} while (0)

#define SB() __builtin_amdgcn_sched_barrier(0)

__device__ __forceinline__ float fast_exp2(float x) {
#if __has_builtin(__builtin_amdgcn_exp2f)
    return __builtin_amdgcn_exp2f(x);
#else
    return exp2f(x);
#endif
}
__device__ __forceinline__ float fast_rcp(float x) {
#if __has_builtin(__builtin_amdgcn_rcpf)
    return __builtin_amdgcn_rcpf(x);
#else
    return 1.0f / x;
#endif
}
__device__ __forceinline__ float fast_tanh(float y) {
    float t = fast_exp2(y * 2.885390081777927f);
    return (t - 1.0f) * fast_rcp(t + 1.0f);
}
__device__ __forceinline__ float fast_sigmoid(float z) {
    float t = fast_exp2(-1.4426950408889634f * z);
    return fast_rcp(1.0f + t);
}

// ---------------------------------------------------------------------------
// Pack 5 weight matrices (fp32 row-major [N][K]) into bf16 MFMA-B-fragment
// order (canonical 16x32 tile: lane = ((k>>3)&3)*16 + (n&15), j = k&7).
// ws layout: Wb(98304) | W1(65536) | W2 | Wa | Wt   (bf16 elems)
// ---------------------------------------------------------------------------
__global__ void prep_pack(const float* __restrict__ Wb, const float* __restrict__ W1,
                          const float* __restrict__ W2, const float* __restrict__ Wa,
                          const float* __restrict__ Wt, unsigned short* __restrict__ ws)
{
    int e = blockIdx.x * 256 + threadIdx.x;
    if (e >= 360448) return;
    const float* src; int K; int base;
    if (e < 98304)       { src = Wb; K = 384; base = 0; }
    else if (e < 163840) { src = W1; K = 256; base = 98304; }
    else if (e < 229376) { src = W2; K = 256; base = 163840; }
    else if (e < 294912) { src = Wa; K = 256; base = 229376; }
    else                 { src = Wt; K = 256; base = 294912; }
    int le   = e - base;
    int j    = le & 7;
    int lane = (le >> 3) & 63;
    int tile = le >> 9;
    int kt   = K >> 5;
    int ks   = tile % kt;
    int nt   = tile / kt;
    int n = nt * 16 + (lane & 15);
    int k = ks * 32 + (lane >> 4) * 8 + j;
    ws[e] = f2bf(src[n * K + k]);
}

// ---------------------------------------------------------------------------
// Fused CfC cell (R22 champion + double-buffered phase-1 chunks, FIXED).
// BM=64 rows/block, 4 waves each owning 64 output cols.
// Weights global->3-deep VGPR rotation br0/br1/br2 (issue-ahead-2, compiler-
// managed waitcnt). Arch ~120 beside 64-AGPR acc at (256,2): no spill.
// Phase-1 chunks DOUBLE-BUFFERED: a 64x64 chunk = 4096 bf16 elems (8KB), so
// buf0 = lds[0,4096) and buf1 = lds[4096,8192)  (R23 bug: buf1 at 2048
// OVERLAPPED buf0 -> absmax 1.2). X region [0,16384) is written only after
// the last chunk barrier. ONE barrier per chunk: 7 barriers vs champion's 13.
// Per chunk c: {2 P1STEPs from buf[c&1] -> WRITE c+1 -> ISSUE c+2 -> barrier}
// (the barrier ending block c-1 guarantees buf[(c+1)&1] was fully consumed).
// LDS 32KB. Flat 44 steps: 0..11 phase 1 (6 chunks x 2), 12..43 phase 2.
// ---------------------------------------------------------------------------
__global__ __launch_bounds__(256, 2) void cfc_fused(
    const float* __restrict__ xin, const float* __restrict__ hx,
    const float* __restrict__ ts,
    const float* __restrict__ bb, const float* __restrict__ b1,
    const float* __restrict__ b2, const float* __restrict__ ba,
    const float* __restrict__ bt,
    const unsigned short* __restrict__ wpk,
    float* __restrict__ out)
{
    __shared__ unsigned short lds[16384];   // 32 KB: chunks 0/4096 overlay X
    const int tid  = threadIdx.x;
    const int lane = tid & 63;
    const int w    = tid >> 6;        // wave id = output-col group (64 cols)
    const int row0 = blockIdx.x * BM;

    v8s br0[4], br1[4], br2[4];       // 3-deep B rotation (48 VGPR)

// load step-S weight tile (4 x 16B/lane, coalesced) into DST regs
#define BLOAD(S, DST) do {                                                    \
    _Pragma("unroll")                                                         \
    for (int i = 0; i < 4; ++i) {                                             \
        size_t goff;                                                          \
        if ((S) < 12) {                                                       \
            goff = (size_t)((w * 4 + i) * 12 + (S)) * 512;                    \
        } else {                                                              \
            int s2_ = (S) - 12, g_ = s2_ >> 3, ks_ = s2_ & 7;                 \
            goff = 98304u + (size_t)i * 65536                                 \
                 + (size_t)((w * 4 + g_) * 8 + ks_) * 512;                    \
        }                                                                     \
        DST[i] = *reinterpret_cast<const v8s*>(wpk + goff + (size_t)lane * 8);\
    }                                                                         \
} while (0)

// 64-col input chunk: 64 rows x 16 v4f/row = 1024 v4f, 4 per thread
#define ISSUE_IN(SRC, LD, BUF) do {                                           \
    _Pragma("unroll")                                                         \
    for (int it = 0; it < 4; ++it) {                                          \
        int i_ = tid + it * 256; int r_ = i_ >> 4; int c4_ = i_ & 15;         \
        BUF[it] = *(reinterpret_cast<const v4f*>((SRC) + (size_t)r_ * (LD)) + c4_); \
    }                                                                         \
} while (0)

// convert + write staged chunk into chunk buffer at elem offset CB
#define WRITE_IN(BUF, CB) do {                                                \
    _Pragma("unroll")                                                         \
    for (int it = 0; it < 4; ++it) {                                          \
        int i_ = tid + it * 256; int r_ = i_ >> 4; int c4_ = i_ & 15;         \
        uint2 pk_;                                                            \
        pk_.x = cvt_pk_bf16(BUF[it][0], BUF[it][1]);                          \
        pk_.y = cvt_pk_bf16(BUF[it][2], BUF[it][3]);                          \
        int idx_ = (((r_ >> 4) * 2 + (c4_ >> 3)) * 64 + ((c4_ >> 1) & 3) * 16 \
                    + (r_ & 15)) * 8 + (c4_ & 1) * 4;                         \
        *reinterpret_cast<uint2*>(&lds[(CB) + idx_]) = pk_;                   \
    }                                                                         \
} while (0)

// phase-1 step: A in-step from chunk buffer CB (k-slice S&1), B from CUR regs
#define P1STEP(S, CB, CUR, PRE) do {                                          \
    BLOAD((S) + 2, PRE);                                                      \
    v8s aa_[4];                                                               \
    _Pragma("unroll")                                                         \
    for (int mt = 0; mt < 4; ++mt)                                            \
        aa_[mt] = *reinterpret_cast<const v8s*>(                              \
                      &lds[(CB) + ((mt * 2 + ((S) & 1)) * 64 + lane) * 8]);   \
    __builtin_amdgcn_s_setprio(1);                                            \
    _Pragma("unroll")                                                         \
    for (int nt = 0; nt < 4; ++nt)                                            \
        _Pragma("unroll")                                                     \
        for (int mt = 0; mt < 4; ++mt)                                        \
            acc[nt][mt] = __builtin_amdgcn_mfma_f32_16x16x32_bf16(            \
                              aa_[mt], CUR[nt], acc[nt][mt], 0, 0, 0);        \
    __builtin_amdgcn_s_setprio(0);                                            \
    SB();                                                                     \
} while (0)

// phase-2 step: A in-step from X LDS, B from CUR regs, prefetch S+2 -> PRE
#define P2STEP(S, KS, CUR, PRE) do {                                          \
    BLOAD((S) + 2, PRE);                                                      \
    v8s aa_[4];                                                               \
    _Pragma("unroll")                                                         \
    for (int mt = 0; mt < 4; ++mt)                                            \
        aa_[mt] = *reinterpret_cast<const v8s*>(                              \
                      &lds[((mt * 8 + (KS)) * 64 + lane) * 8]);               \
    __builtin_amdgcn_s_setprio(1);                                            \
    _Pragma("unroll")                                                         \
    for (int mat = 0; mat < 4; ++mat)                                         \
        _Pragma("unroll")                                                     \
        for (int mt = 0; mt < 4; ++mt)                                        \
            a2[mat][mt] = __builtin_amdgcn_mfma_f32_16x16x32_bf16(            \
                              aa_[mt], CUR[mat], a2[mat][mt], 0, 0, 0);       \
    __builtin_amdgcn_s_setprio(0);                                            \
    SB();                                                                     \
} while (0)

// tail variant: no weight prefetch
#define P2STEP_NS(S, KS, CUR) do {                                            \
    v8s aa_[4];                                                               \
    _Pragma("unroll")                                                         \
    for (int mt = 0; mt < 4; ++mt)                                            \
        aa_[mt] = *reinterpret_cast<const v8s*>(                              \
                      &lds[((mt * 8 + (KS)) * 64 + lane) * 8]);               \
    __builtin_amdgcn_s_setprio(1);                                            \
    _Pragma("unroll")                                                         \
    for (int mat = 0; mat < 4; ++mat)                                         \
        _Pragma("unroll")                                                     \
        for (int mt = 0; mt < 4; ++mt)                                        \
            a2[mat][mt] = __builtin_amdgcn_mfma_f32_16x16x32_bf16(            \
                              aa_[mt], CUR[mat], a2[mat][mt], 0, 0, 0);       \
    __builtin_amdgcn_s_setprio(0);                                            \
    SB();                                                                     \
} while (0)

#define GINIT(G) do {                                                         \
    const int n_ = w * 64 + (G) * 16 + (lane & 15);                           \
    float v1_ = b1[n_], v2_ = b2[n_], va_ = ba[n_], vt_ = bt[n_];             \
    v4f q1_ = {v1_,v1_,v1_,v1_}, q2_ = {v2_,v2_,v2_,v2_};                     \
    v4f qa_ = {va_,va_,va_,va_}, qt_ = {vt_,vt_,vt_,vt_};                     \
    _Pragma("unroll")                                                         \
    for (int mt = 0; mt < 4; ++mt) {                                          \
        a2[0][mt] = q1_; a2[1][mt] = q2_; a2[2][mt] = qa_; a2[3][mt] = qt_;   \
    }                                                                         \
} while (0)

#define EPI(G) do {                                                           \
    const int n_ = w * 64 + (G) * 16 + (lane & 15);                           \
    _Pragma("unroll")                                                         \
    for (int mt = 0; mt < 4; ++mt) {                                          \
        int rowb_ = row0 + mt * 16 + ((lane >> 4) << 2);                      \
        v4f tsv_ = *reinterpret_cast<const v4f*>(&ts[rowb_]);                 \
        _Pragma("unroll")                                                     \
        for (int r = 0; r < 4; ++r) {                                         \
            float ff1_ = fast_tanh(a2[0][mt][r]);                             \
            float ff2_ = fast_tanh(a2[1][mt][r]);                             \
            float ti_  = fast_sigmoid(a2[2][mt][r] * tsv_[r] + a2[3][mt][r]); \
            out[(size_t)(rowb_ + r) * 256 + n_] = ff1_ + ti_ * (ff2_ - ff1_); \
        }                                                                     \
    }                                                                         \
} while (0)

    // ---------------- phase 1: backbone GEMM, acc[nt][mt] -------------------
    v4f acc[4][4];
    #pragma unroll
    for (int nt = 0; nt < 4; ++nt) {
        float bv = bb[w * 64 + nt * 16 + (lane & 15)];
        v4f bvv = {bv, bv, bv, bv};
        #pragma unroll
        for (int mt = 0; mt < 4; ++mt) acc[nt][mt] = bvv;
    }

    v4f sA[4];
    // prologue: chunk 0 staged into buf0, chunk 1 loads in flight
    ISSUE_IN(xin + (size_t)row0 * 128, 128, sA);
    BLOAD(0, br0); BLOAD(1, br1);       // weight pipeline: 2 tiles in flight
    WRITE_IN(sA, 0);
    ISSUE_IN(xin + (size_t)row0 * 128 + 64, 128, sA);     // chunk 1
    LDS_BARRIER();                      // chunk 0 visible

    // block 0: compute c0 (buf0), write c1 (buf1), issue c2
    P1STEP(0, 0, br0, br2); P1STEP(1, 0, br1, br0);
    WRITE_IN(sA, 4096);
    ISSUE_IN(hx + (size_t)row0 * 256, 256, sA);           // chunk 2
    LDS_BARRIER();                      // c1 visible; c0 consumed by all

    // block 1: compute c1 (buf1), write c2 (buf0), issue c3
    P1STEP(2, 4096, br2, br1); P1STEP(3, 4096, br0, br2);
    WRITE_IN(sA, 0);
    ISSUE_IN(hx + (size_t)row0 * 256 + 64, 256, sA);      // chunk 3
    LDS_BARRIER();

    // block 2: compute c2 (buf0), write c3 (buf1), issue c4
    P1STEP(4, 0, br1, br0); P1STEP(5, 0, br2, br1);
    WRITE_IN(sA, 4096);
    ISSUE_IN(hx + (size_t)row0 * 256 + 128, 256, sA);     // chunk 4
    LDS_BARRIER();

    // block 3: compute c3 (buf1), write c4 (buf0), issue c5
    P1STEP(6, 4096, br0, br2); P1STEP(7, 4096, br1, br0);
    WRITE_IN(sA, 0);
    ISSUE_IN(hx + (size_t)row0 * 256 + 192, 256, sA);     // chunk 5
    LDS_BARRIER();

    // block 4: compute c4 (buf0), write c5 (buf1)
    P1STEP(8, 0, br2, br1); P1STEP(9, 0, br0, br2);
    WRITE_IN(sA, 4096);
    LDS_BARRIER();

    // block 5: compute c5 (buf1)
    P1STEP(10, 4096, br1, br0); P1STEP(11, 4096, br2, br1);
    LDS_BARRIER();                  // all waves done reading chunk buffers

    // ------------- activation + write X to LDS in packed A-frag layout ------
    #pragma unroll
    for (int nt = 0; nt < 4; ++nt)
        #pragma unroll
        for (int mt = 0; mt < 4; ++mt)
            #pragma unroll
            for (int r = 0; r < 4; ++r) {
                float xv = 1.7159f * fast_tanh(0.666f * acc[nt][mt][r]);
                int idx = ((mt*8 + w*2 + (nt >> 1)) * 64
                           + ((nt & 1)*2 + ((lane >> 3) & 1)) * 16 + (lane >> 4)*4 + r) * 8
                          + (lane & 7);
                lds[idx] = f2bf(xv);
            }
    LDS_BARRIER();                  // X visible to all waves

    // ---------------- phase 2: 4 GEMMs over X + fused epilogue --------------
    v4f a2[4][4];
    GINIT(0);
    P2STEP(12,0, br0, br2); P2STEP(13,1, br1, br0);
    P2STEP(14,2, br2, br1); P2STEP(15,3, br0, br2);
    P2STEP(16,4, br1, br0); P2STEP(17,5, br2, br1);
    P2STEP(18,6, br0, br2); P2STEP(19,7, br1, br0);
    EPI(0);
    GINIT(1);
    P2STEP(20,0, br2, br1); P2STEP(21,1, br0, br2);
    P2STEP(22,2, br1, br0); P2STEP(23,3, br2, br1);
    P2STEP(24,4, br0, br2); P2STEP(25,5, br1, br0);
    P2STEP(26,6, br2, br1); P2STEP(27,7, br0, br2);
    EPI(1);
    GINIT(2);
    P2STEP(28,0, br1, br0); P2STEP(29,1, br2, br1);
    P2STEP(30,2, br0, br2); P2STEP(31,3, br1, br0);
    P2STEP(32,4, br2, br1); P2STEP(33,5, br0, br2);
    P2STEP(34,6, br1, br0); P2STEP(35,7, br2, br1);
    EPI(2);
    GINIT(3);
    P2STEP(36,0, br0, br2); P2STEP(37,1, br1, br0);
    P2STEP(38,2, br2, br1); P2STEP(39,3, br0, br2);
    P2STEP(40,4, br1, br0); P2STEP(41,5, br2, br1);
    P2STEP_NS(42,6, br0);   P2STEP_NS(43,7, br1);
    EPI(3);

#undef BLOAD
#undef ISSUE_IN
#undef WRITE_IN
#undef P1STEP
#undef P2STEP
#undef P2STEP_NS
#undef GINIT
#undef EPI
}

extern "C" void kernel_launch(void* const* d_in, const int* in_sizes, int n_in,
                              void* d_out, int out_size, void* d_ws, size_t ws_size,
                              hipStream_t stream)
{
    const float* xin = (const float*)d_in[0];
    const float* hx  = (const float*)d_in[1];
    const float* ts  = (const float*)d_in[2];
    const float* Wb  = (const float*)d_in[3];
    const float* bb  = (const float*)d_in[4];
    const float* W1  = (const float*)d_in[5];
    const float* b1  = (const float*)d_in[6];
    const float* W2  = (const float*)d_in[7];
    const float* b2  = (const float*)d_in[8];
    const float* Wa  = (const float*)d_in[9];
    const float* ba  = (const float*)d_in[10];
    const float* Wt  = (const float*)d_in[11];
    const float* bt  = (const float*)d_in[12];

    if (ws_size < 360448 * sizeof(unsigned short)) return;
    unsigned short* wpk = (unsigned short*)d_ws;

    prep_pack<<<1408, 256, 0, stream>>>(Wb, W1, W2, Wa, Wt, wpk);
    cfc_fused<<<1024, 256, 0, stream>>>(xin, hx, ts, bb, b1, b2, ba, bt, wpk,
                                        (float*)d_out);
}

// Round 25
// 63.684 us; speedup vs baseline: 1.9421x; 1.0403x over previous
//
#include <hip/hip_runtime.h>

typedef float v4f __attribute__((ext_vector_type(4)));
typedef short v8s __attribute__((ext_vector_type(8)));

#define BM 64

__device__ __forceinline__ unsigned short f2bf(float f) {
    union { float f; unsigned u; } v; v.f = f;
    unsigned u = v.u;
    u += 0x7FFFu + ((u >> 16) & 1u);   // round-to-nearest-even
    return (unsigned short)(u >> 16);
}

// pack two f32 -> two bf16 (RNE) in one instruction
__device__ __forceinline__ unsigned cvt_pk_bf16(float lo, float hi) {
    unsigned r;
    asm("v_cvt_pk_bf16_f32 %0, %1, %2" : "=v"(r) : "v"(lo), "v"(hi));
    return r;
}

// shared-LDS sync WITHOUT draining vmcnt: only lgkm (ds ops) must complete;
// in-flight global loads into registers survive the barrier.
#define LDS_BARRIER() do {                                        \
    asm volatile("s_waitcnt lgkmcnt(0)" ::: "memory");            \
    __builtin_amdgcn_s_barrier();                                 \
    __builtin_amdgcn_sched_barrier(0);                            \
} while (0)

#define SB() __builtin_amdgcn_sched_barrier(0)

__device__ __forceinline__ float fast_exp2(float x) {
#if __has_builtin(__builtin_amdgcn_exp2f)
    return __builtin_amdgcn_exp2f(x);
#else
    return exp2f(x);
#endif
}
__device__ __forceinline__ float fast_rcp(float x) {
#if __has_builtin(__builtin_amdgcn_rcpf)
    return __builtin_amdgcn_rcpf(x);
#else
    return 1.0f / x;
#endif
}
__device__ __forceinline__ float fast_tanh(float y) {
    float t = fast_exp2(y * 2.885390081777927f);
    return (t - 1.0f) * fast_rcp(t + 1.0f);
}

// ---------------------------------------------------------------------------
// Pack 5 weight matrices (fp32 row-major [N][K]) into bf16 MFMA-B-fragment
// order (canonical 16x32 tile: lane = ((k>>3)&3)*16 + (n&15), j = k&7).
// ws layout: Wb(98304) | W1(65536) | W2 | Wa | Wt   (bf16 elems)
// ---------------------------------------------------------------------------
__global__ void prep_pack(const float* __restrict__ Wb, const float* __restrict__ W1,
                          const float* __restrict__ W2, const float* __restrict__ Wa,
                          const float* __restrict__ Wt, unsigned short* __restrict__ ws)
{
    int e = blockIdx.x * 256 + threadIdx.x;
    if (e >= 360448) return;
    const float* src; int K; int base;
    if (e < 98304)       { src = Wb; K = 384; base = 0; }
    else if (e < 163840) { src = W1; K = 256; base = 98304; }
    else if (e < 229376) { src = W2; K = 256; base = 163840; }
    else if (e < 294912) { src = Wa; K = 256; base = 229376; }
    else                 { src = Wt; K = 256; base = 294912; }
    int le   = e - base;
    int j    = le & 7;
    int lane = (le >> 3) & 63;
    int tile = le >> 9;
    int kt   = K >> 5;
    int ks   = tile % kt;
    int nt   = tile / kt;
    int n = nt * 16 + (lane & 15);
    int k = ks * 32 + (lane >> 4) * 8 + j;
    ws[e] = f2bf(src[n * K + k]);
}

// ---------------------------------------------------------------------------
// Fused CfC cell (R24 champion + single-rcp fused epilogue).
// BM=64 rows/block, 4 waves each owning 64 output cols.
// Weights global->3-deep VGPR rotation br0/br1/br2 (issue-ahead-2, compiler-
// managed waitcnt). Arch ~120 beside 64-AGPR acc at (256,2): no spill.
// Phase-1 chunks double-buffered at lds elem 0/4096 (one barrier per chunk).
// Epilogue algebra: out = ff1 + ti*(ff2-ff1)
//                       = 1 - 2*(1 + t1 + t3 + t2*t3) / [(t1+1)(t2+1)(t3+1)]
// with t1=e^{2p}, t2=e^{2q}, t3=e^{-z} -- 3 exp + ONE rcp per output
// (was 3 exp + 3 rcp). Safe: xavier pre-acts ~N(0,1) -> t <= ~2^15.
// LDS 32KB. Flat 44 steps: 0..11 phase 1 (6 chunks x 2), 12..43 phase 2.
// ---------------------------------------------------------------------------
__global__ __launch_bounds__(256, 2) void cfc_fused(
    const float* __restrict__ xin, const float* __restrict__ hx,
    const float* __restrict__ ts,
    const float* __restrict__ bb, const float* __restrict__ b1,
    const float* __restrict__ b2, const float* __restrict__ ba,
    const float* __restrict__ bt,
    const unsigned short* __restrict__ wpk,
    float* __restrict__ out)
{
    __shared__ unsigned short lds[16384];   // 32 KB: chunks 0/4096 overlay X
    const int tid  = threadIdx.x;
    const int lane = tid & 63;
    const int w    = tid >> 6;        // wave id = output-col group (64 cols)
    const int row0 = blockIdx.x * BM;

    v8s br0[4], br1[4], br2[4];       // 3-deep B rotation (48 VGPR)

// load step-S weight tile (4 x 16B/lane, coalesced) into DST regs
#define BLOAD(S, DST) do {                                                    \
    _Pragma("unroll")                                                         \
    for (int i = 0; i < 4; ++i) {                                             \
        size_t goff;                                                          \
        if ((S) < 12) {                                                       \
            goff = (size_t)((w * 4 + i) * 12 + (S)) * 512;                    \
        } else {                                                              \
            int s2_ = (S) - 12, g_ = s2_ >> 3, ks_ = s2_ & 7;                 \
            goff = 98304u + (size_t)i * 65536                                 \
                 + (size_t)((w * 4 + g_) * 8 + ks_) * 512;                    \
        }                                                                     \
        DST[i] = *reinterpret_cast<const v8s*>(wpk + goff + (size_t)lane * 8);\
    }                                                                         \
} while (0)

// 64-col input chunk: 64 rows x 16 v4f/row = 1024 v4f, 4 per thread
#define ISSUE_IN(SRC, LD, BUF) do {                                           \
    _Pragma("unroll")                                                         \
    for (int it = 0; it < 4; ++it) {                                          \
        int i_ = tid + it * 256; int r_ = i_ >> 4; int c4_ = i_ & 15;         \
        BUF[it] = *(reinterpret_cast<const v4f*>((SRC) + (size_t)r_ * (LD)) + c4_); \
    }                                                                         \
} while (0)

// convert + write staged chunk into chunk buffer at elem offset CB
#define WRITE_IN(BUF, CB) do {                                                \
    _Pragma("unroll")                                                         \
    for (int it = 0; it < 4; ++it) {                                          \
        int i_ = tid + it * 256; int r_ = i_ >> 4; int c4_ = i_ & 15;         \
        uint2 pk_;                                                            \
        pk_.x = cvt_pk_bf16(BUF[it][0], BUF[it][1]);                          \
        pk_.y = cvt_pk_bf16(BUF[it][2], BUF[it][3]);                          \
        int idx_ = (((r_ >> 4) * 2 + (c4_ >> 3)) * 64 + ((c4_ >> 1) & 3) * 16 \
                    + (r_ & 15)) * 8 + (c4_ & 1) * 4;                         \
        *reinterpret_cast<uint2*>(&lds[(CB) + idx_]) = pk_;                   \
    }                                                                         \
} while (0)

// phase-1 step: A in-step from chunk buffer CB (k-slice S&1), B from CUR regs
#define P1STEP(S, CB, CUR, PRE) do {                                          \
    BLOAD((S) + 2, PRE);                                                      \
    v8s aa_[4];                                                               \
    _Pragma("unroll")                                                         \
    for (int mt = 0; mt < 4; ++mt)                                            \
        aa_[mt] = *reinterpret_cast<const v8s*>(                              \
                      &lds[(CB) + ((mt * 2 + ((S) & 1)) * 64 + lane) * 8]);   \
    __builtin_amdgcn_s_setprio(1);                                            \
    _Pragma("unroll")                                                         \
    for (int nt = 0; nt < 4; ++nt)                                            \
        _Pragma("unroll")                                                     \
        for (int mt = 0; mt < 4; ++mt)                                        \
            acc[nt][mt] = __builtin_amdgcn_mfma_f32_16x16x32_bf16(            \
                              aa_[mt], CUR[nt], acc[nt][mt], 0, 0, 0);        \
    __builtin_amdgcn_s_setprio(0);                                            \
    SB();                                                                     \
} while (0)

// phase-2 step: A in-step from X LDS, B from CUR regs, prefetch S+2 -> PRE
#define P2STEP(S, KS, CUR, PRE) do {                                          \
    BLOAD((S) + 2, PRE);                                                      \
    v8s aa_[4];                                                               \
    _Pragma("unroll")                                                         \
    for (int mt = 0; mt < 4; ++mt)                                            \
        aa_[mt] = *reinterpret_cast<const v8s*>(                              \
                      &lds[((mt * 8 + (KS)) * 64 + lane) * 8]);               \
    __builtin_amdgcn_s_setprio(1);                                            \
    _Pragma("unroll")                                                         \
    for (int mat = 0; mat < 4; ++mat)                                         \
        _Pragma("unroll")                                                     \
        for (int mt = 0; mt < 4; ++mt)                                        \
            a2[mat][mt] = __builtin_amdgcn_mfma_f32_16x16x32_bf16(            \
                              aa_[mt], CUR[mat], a2[mat][mt], 0, 0, 0);       \
    __builtin_amdgcn_s_setprio(0);                                            \
    SB();                                                                     \
} while (0)

// tail variant: no weight prefetch
#define P2STEP_NS(S, KS, CUR) do {                                            \
    v8s aa_[4];                                                               \
    _Pragma("unroll")                                                         \
    for (int mt = 0; mt < 4; ++mt)                                            \
        aa_[mt] = *reinterpret_cast<const v8s*>(                              \
                      &lds[((mt * 8 + (KS)) * 64 + lane) * 8]);               \
    __builtin_amdgcn_s_setprio(1);                                            \
    _Pragma("unroll")                                                         \
    for (int mat = 0; mat < 4; ++mat)                                         \
        _Pragma("unroll")                                                     \
        for (int mt = 0; mt < 4; ++mt)                                        \
            a2[mat][mt] = __builtin_amdgcn_mfma_f32_16x16x32_bf16(            \
                              aa_[mt], CUR[mat], a2[mat][mt], 0, 0, 0);       \
    __builtin_amdgcn_s_setprio(0);                                            \
    SB();                                                                     \
} while (0)

#define GINIT(G) do {                                                         \
    const int n_ = w * 64 + (G) * 16 + (lane & 15);                           \
    float v1_ = b1[n_], v2_ = b2[n_], va_ = ba[n_], vt_ = bt[n_];             \
    v4f q1_ = {v1_,v1_,v1_,v1_}, q2_ = {v2_,v2_,v2_,v2_};                     \
    v4f qa_ = {va_,va_,va_,va_}, qt_ = {vt_,vt_,vt_,vt_};                     \
    _Pragma("unroll")                                                         \
    for (int mt = 0; mt < 4; ++mt) {                                          \
        a2[0][mt] = q1_; a2[1][mt] = q2_; a2[2][mt] = qa_; a2[3][mt] = qt_;   \
    }                                                                         \
} while (0)

// fused epilogue: single-rcp blend.  t1=e^{2p}, t2=e^{2q}, t3=e^{-z};
// out = 1 - 2*(1 + t1 + t3 + t2*t3) / ((t1+1)(t2+1)(t3+1))
#define EPI(G) do {                                                           \
    const int n_ = w * 64 + (G) * 16 + (lane & 15);                           \
    _Pragma("unroll")                                                         \
    for (int mt = 0; mt < 4; ++mt) {                                          \
        int rowb_ = row0 + mt * 16 + ((lane >> 4) << 2);                      \
        v4f tsv_ = *reinterpret_cast<const v4f*>(&ts[rowb_]);                 \
        _Pragma("unroll")                                                     \
        for (int r = 0; r < 4; ++r) {                                         \
            float z_  = a2[2][mt][r] * tsv_[r] + a2[3][mt][r];                \
            float t1_ = fast_exp2(a2[0][mt][r] * 2.885390081777927f);         \
            float t2_ = fast_exp2(a2[1][mt][r] * 2.885390081777927f);         \
            float t3_ = fast_exp2(-1.4426950408889634f * z_);                 \
            float nu_ = 1.0f + t1_ + t3_ + t2_ * t3_;                         \
            float de_ = (t1_ + 1.0f) * (t2_ + 1.0f) * (t3_ + 1.0f);           \
            out[(size_t)(rowb_ + r) * 256 + n_] =                             \
                1.0f - 2.0f * nu_ * fast_rcp(de_);                            \
        }                                                                     \
    }                                                                         \
} while (0)

    // ---------------- phase 1: backbone GEMM, acc[nt][mt] -------------------
    v4f acc[4][4];
    #pragma unroll
    for (int nt = 0; nt < 4; ++nt) {
        float bv = bb[w * 64 + nt * 16 + (lane & 15)];
        v4f bvv = {bv, bv, bv, bv};
        #pragma unroll
        for (int mt = 0; mt < 4; ++mt) acc[nt][mt] = bvv;
    }

    v4f sA[4];
    // prologue: chunk 0 staged into buf0, chunk 1 loads in flight
    ISSUE_IN(xin + (size_t)row0 * 128, 128, sA);
    BLOAD(0, br0); BLOAD(1, br1);       // weight pipeline: 2 tiles in flight
    WRITE_IN(sA, 0);
    ISSUE_IN(xin + (size_t)row0 * 128 + 64, 128, sA);     // chunk 1
    LDS_BARRIER();                      // chunk 0 visible

    // block 0: compute c0 (buf0), write c1 (buf1), issue c2
    P1STEP(0, 0, br0, br2); P1STEP(1, 0, br1, br0);
    WRITE_IN(sA, 4096);
    ISSUE_IN(hx + (size_t)row0 * 256, 256, sA);           // chunk 2
    LDS_BARRIER();                      // c1 visible; c0 consumed by all

    // block 1: compute c1 (buf1), write c2 (buf0), issue c3
    P1STEP(2, 4096, br2, br1); P1STEP(3, 4096, br0, br2);
    WRITE_IN(sA, 0);
    ISSUE_IN(hx + (size_t)row0 * 256 + 64, 256, sA);      // chunk 3
    LDS_BARRIER();

    // block 2: compute c2 (buf0), write c3 (buf1), issue c4
    P1STEP(4, 0, br1, br0); P1STEP(5, 0, br2, br1);
    WRITE_IN(sA, 4096);
    ISSUE_IN(hx + (size_t)row0 * 256 + 128, 256, sA);     // chunk 4
    LDS_BARRIER();

    // block 3: compute c3 (buf1), write c4 (buf0), issue c5
    P1STEP(6, 4096, br0, br2); P1STEP(7, 4096, br1, br0);
    WRITE_IN(sA, 0);
    ISSUE_IN(hx + (size_t)row0 * 256 + 192, 256, sA);     // chunk 5
    LDS_BARRIER();

    // block 4: compute c4 (buf0), write c5 (buf1)
    P1STEP(8, 0, br2, br1); P1STEP(9, 0, br0, br2);
    WRITE_IN(sA, 4096);
    LDS_BARRIER();

    // block 5: compute c5 (buf1)
    P1STEP(10, 4096, br1, br0); P1STEP(11, 4096, br2, br1);
    LDS_BARRIER();                  // all waves done reading chunk buffers

    // ------------- activation + write X to LDS in packed A-frag layout ------
    #pragma unroll
    for (int nt = 0; nt < 4; ++nt)
        #pragma unroll
        for (int mt = 0; mt < 4; ++mt)
            #pragma unroll
            for (int r = 0; r < 4; ++r) {
                float xv = 1.7159f * fast_tanh(0.666f * acc[nt][mt][r]);
                int idx = ((mt*8 + w*2 + (nt >> 1)) * 64
                           + ((nt & 1)*2 + ((lane >> 3) & 1)) * 16 + (lane >> 4)*4 + r) * 8
                          + (lane & 7);
                lds[idx] = f2bf(xv);
            }
    LDS_BARRIER();                  // X visible to all waves

    // ---------------- phase 2: 4 GEMMs over X + fused epilogue --------------
    v4f a2[4][4];
    GINIT(0);
    P2STEP(12,0, br0, br2); P2STEP(13,1, br1, br0);
    P2STEP(14,2, br2, br1); P2STEP(15,3, br0, br2);
    P2STEP(16,4, br1, br0); P2STEP(17,5, br2, br1);
    P2STEP(18,6, br0, br2); P2STEP(19,7, br1, br0);
    EPI(0);
    GINIT(1);
    P2STEP(20,0, br2, br1); P2STEP(21,1, br0, br2);
    P2STEP(22,2, br1, br0); P2STEP(23,3, br2, br1);
    P2STEP(24,4, br0, br2); P2STEP(25,5, br1, br0);
    P2STEP(26,6, br2, br1); P2STEP(27,7, br0, br2);
    EPI(1);
    GINIT(2);
    P2STEP(28,0, br1, br0); P2STEP(29,1, br2, br1);
    P2STEP(30,2, br0, br2); P2STEP(31,3, br1, br0);
    P2STEP(32,4, br2, br1); P2STEP(33,5, br0, br2);
    P2STEP(34,6, br1, br0); P2STEP(35,7, br2, br1);
    EPI(2);
    GINIT(3);
    P2STEP(36,0, br0, br2); P2STEP(37,1, br1, br0);
    P2STEP(38,2, br2, br1); P2STEP(39,3, br0, br2);
    P2STEP(40,4, br1, br0); P2STEP(41,5, br2, br1);
    P2STEP_NS(42,6, br0);   P2STEP_NS(43,7, br1);
    EPI(3);

#undef BLOAD
#undef ISSUE_IN
#undef WRITE_IN
#undef P1STEP
#undef P2STEP
#undef P2STEP_NS
#undef GINIT
#undef EPI
}

extern "C" void kernel_launch(void* const* d_in, const int* in_sizes, int n_in,
                              void* d_out, int out_size, void* d_ws, size_t ws_size,
                              hipStream_t stream)
{
    const float* xin = (const float*)d_in[0];
    const float* hx  = (const float*)d_in[1];
    const float* ts  = (const float*)d_in[2];
    const float* Wb  = (const float*)d_in[3];
    const float* bb  = (const float*)d_in[4];
    const float* W1  = (const float*)d_in[5];
    const float* b1  = (const float*)d_in[6];
    const float* W2  = (const float*)d_in[7];
    const float* b2  = (const float*)d_in[8];
    const float* Wa  = (const float*)d_in[9];
    const float* ba  = (const float*)d_in[10];
    const float* Wt  = (const float*)d_in[11];
    const float* bt  = (const float*)d_in[12];

    if (ws_size < 360448 * sizeof(unsigned short)) return;
    unsigned short* wpk = (unsigned short*)d_ws;

    prep_pack<<<1408, 256, 0, stream>>>(Wb, W1, W2, Wa, Wt, wpk);
    cfc_fused<<<1024, 256, 0, stream>>>(xin, hx, ts, bb, b1, b2, ba, bt, wpk,
                                        (float*)d_out);
}